// Round 4
// baseline (682.005 us; speedup 1.0000x reference)
//
#include <hip/hip_runtime.h>
#include <math.h>

// Problem constants
#define NPROJ 4112          // P = 2*H*K + H*V + 2*H + UNITS
#define HOFF  0                                  // h_t  : 512*1024
#define COFF  524288                             // C_t  : 512*8*128*128
#define NOFF  67633152                           // n_t  : 512*1024

// ---------------------------------------------------------------------------
// Kernel 1: proj[:, 0:4096] = X0@W0 + X1@W1 + bias
// BM=64, BN=64, BK=32, 256 threads, 4x4/thread.
// LDS double-buffered, ONE barrier per K-step, reg-staged prefetch so the
// global-load latency hides under the 512-FMA compute block.
// fp32 FMA chunks of 32 k-terms flushed into fp64 accumulators (absmax-proven).
// Grid (64,8) = 512 blocks = exactly 2 blocks/CU (balanced; no 2.03x tail).
// ---------------------------------------------------------------------------
__global__ __launch_bounds__(256)
void proj_gemm(const float* __restrict__ X0, const float* __restrict__ X1,
               const float* __restrict__ W0, const float* __restrict__ W1,
               const float* __restrict__ bias, float* __restrict__ proj)
{
    const int N = NPROJ;
    const int K = 1024;
    __shared__ float As[2][32][68];   // [buf][k][row]
    __shared__ float Bs[2][32][68];   // [buf][k][col]

    const int tid  = threadIdx.x;
    const int row0 = blockIdx.y * 64;
    const int col0 = blockIdx.x * 64;          // 0..4032; cols always < 4096
    const int tx   = tid & 15;
    const int ty   = tid >> 4;

    // staging assignment
    const int ar = tid >> 2;                   // A row 0..63
    const int aq = (tid & 3) << 2;             // A k-quad base {0,4,8,12}
    const int bk = tid >> 4;                   // B k-row 0..15
    const int bn = (tid & 15) << 2;            // B col {0..60}

    float  acc32[4][4];
    double acc64[4][4];
#pragma unroll
    for (int i = 0; i < 4; ++i)
#pragma unroll
        for (int j = 0; j < 4; ++j) { acc32[i][j] = 0.f; acc64[i][j] = 0.0; }

    // tile t in 0..63 : src = t>>5, k0 = (t&31)<<5
#define A_PTR(t, ofs) (((t) & 32 ? X1 : X0) + (size_t)(row0 + ar) * K + (((t) & 31) << 5) + aq + (ofs))
#define B_PTR(t, ofs) (((t) & 32 ? W1 : W0) + (size_t)((((t) & 31) << 5) + bk + (ofs)) * N + col0 + bn)

    // prologue: stage tile 0 into buf 0
    {
        const float4 a0 = *(const float4*)A_PTR(0, 0);
        const float4 a1 = *(const float4*)A_PTR(0, 16);
        const float4 b0 = *(const float4*)B_PTR(0, 0);
        const float4 b1 = *(const float4*)B_PTR(0, 16);
        As[0][aq + 0][ar] = a0.x; As[0][aq + 1][ar] = a0.y;
        As[0][aq + 2][ar] = a0.z; As[0][aq + 3][ar] = a0.w;
        As[0][aq + 16][ar] = a1.x; As[0][aq + 17][ar] = a1.y;
        As[0][aq + 18][ar] = a1.z; As[0][aq + 19][ar] = a1.w;
        *(float4*)&Bs[0][bk][bn]      = b0;
        *(float4*)&Bs[0][bk + 16][bn] = b1;
    }
    __syncthreads();

#define STEP(CUR, T)                                                            \
    {                                                                           \
        float4 a0, a1, b0, b1;                                                  \
        const bool more = (T) + 1 < 64;                                         \
        if (more) {                                                             \
            a0 = *(const float4*)A_PTR((T) + 1, 0);                             \
            a1 = *(const float4*)A_PTR((T) + 1, 16);                            \
            b0 = *(const float4*)B_PTR((T) + 1, 0);                             \
            b1 = *(const float4*)B_PTR((T) + 1, 16);                            \
        }                                                                       \
        _Pragma("unroll")                                                       \
        for (int kk = 0; kk < 32; ++kk) {                                       \
            const float4 av = *(const float4*)&As[CUR][kk][ty << 2];            \
            const float4 bv = *(const float4*)&Bs[CUR][kk][tx << 2];            \
            const float aa[4] = {av.x, av.y, av.z, av.w};                       \
            const float bb[4] = {bv.x, bv.y, bv.z, bv.w};                       \
            _Pragma("unroll")                                                   \
            for (int i = 0; i < 4; ++i)                                         \
                _Pragma("unroll")                                               \
                for (int j = 0; j < 4; ++j)                                     \
                    acc32[i][j] = fmaf(aa[i], bb[j], acc32[i][j]);              \
        }                                                                       \
        if (more) {                                                             \
            As[CUR ^ 1][aq + 0][ar] = a0.x; As[CUR ^ 1][aq + 1][ar] = a0.y;     \
            As[CUR ^ 1][aq + 2][ar] = a0.z; As[CUR ^ 1][aq + 3][ar] = a0.w;     \
            As[CUR ^ 1][aq + 16][ar] = a1.x; As[CUR ^ 1][aq + 17][ar] = a1.y;   \
            As[CUR ^ 1][aq + 18][ar] = a1.z; As[CUR ^ 1][aq + 19][ar] = a1.w;   \
            *(float4*)&Bs[CUR ^ 1][bk][bn]      = b0;                           \
            *(float4*)&Bs[CUR ^ 1][bk + 16][bn] = b1;                           \
        }                                                                       \
        _Pragma("unroll")                                                       \
        for (int i = 0; i < 4; ++i)                                             \
            _Pragma("unroll")                                                   \
            for (int j = 0; j < 4; ++j) {                                       \
                acc64[i][j] += (double)acc32[i][j];                             \
                acc32[i][j] = 0.f;                                              \
            }                                                                   \
        __syncthreads();                                                        \
    }

    for (int t = 0; t < 64; t += 2) {
        STEP(0, t)
        STEP(1, t + 1)
    }
#undef STEP
#undef A_PTR
#undef B_PTR

    // epilogue: + bias (fp64), round to fp32, float4 store (cols < 4096)
    const int c = col0 + (tx << 2);
#pragma unroll
    for (int i = 0; i < 4; ++i) {
        const int row = row0 + (ty << 2) + i;
        float4 w;
        w.x = (float)(acc64[i][0] + (double)bias[c + 0]);
        w.y = (float)(acc64[i][1] + (double)bias[c + 1]);
        w.z = (float)(acc64[i][2] + (double)bias[c + 2]);
        w.w = (float)(acc64[i][3] + (double)bias[c + 3]);
        *(float4*)(proj + (size_t)row * N + c) = w;
    }
}

// ---------------------------------------------------------------------------
// Kernel 1b: tail columns 4096..4111 (o_g tail — cancellation-insensitive).
// 32 blocks x 256 threads; thread = (row, col), 4-way-ILP fp32 chunks -> fp64.
// ---------------------------------------------------------------------------
__global__ __launch_bounds__(256)
void proj_tail(const float* __restrict__ X0, const float* __restrict__ X1,
               const float* __restrict__ W0, const float* __restrict__ W1,
               const float* __restrict__ bias, float* __restrict__ proj)
{
    const int tid = threadIdx.x;
    const int r   = (blockIdx.x << 4) + (tid >> 4);   // 0..511
    const int c   = 4096 + (tid & 15);
    double acc = 0.0;
    for (int src = 0; src < 2; ++src) {
        const float* __restrict__ X = src ? X1 : X0;
        const float* __restrict__ W = src ? W1 : W0;
        const float* __restrict__ xr = X + (size_t)r * 1024;
        for (int kc = 0; kc < 4; ++kc) {
            float s0 = 0.f, s1 = 0.f, s2 = 0.f, s3 = 0.f;
            const int kend = (kc << 8) + 256;
#pragma unroll 8
            for (int k = kc << 8; k < kend; k += 4) {
                const float4 xv = *(const float4*)(xr + k);
                s0 = fmaf(xv.x, W[(size_t)(k + 0) * NPROJ + c], s0);
                s1 = fmaf(xv.y, W[(size_t)(k + 1) * NPROJ + c], s1);
                s2 = fmaf(xv.z, W[(size_t)(k + 2) * NPROJ + c], s2);
                s3 = fmaf(xv.w, W[(size_t)(k + 3) * NPROJ + c], s3);
            }
            acc += (double)((s0 + s1) + (s2 + s3));
        }
    }
    proj[(size_t)r * NPROJ + c] = (float)(acc + (double)bias[c]);
}

// ---------------------------------------------------------------------------
// Kernel 2: fused mLSTM state update. One block per (b,h) pair (4096 blocks).
// fp64 for all cancellation-sensitive math; HBM-bound at ~6.9 TB/s effective.
// ---------------------------------------------------------------------------
__global__ __launch_bounds__(256)
void mlstm_update(const float* __restrict__ proj, const float* __restrict__ C_tm1,
                  const float* __restrict__ n_tm1, float* __restrict__ out)
{
    const int bh = blockIdx.x;
    const int b  = bh >> 3;
    const int h  = bh & 7;
    const int t  = threadIdx.x;
    const float* __restrict__ pr = proj + (size_t)b * NPROJ;

    __shared__ double q_s[128];
    __shared__ double coef_s[128];   // i_g * k[kk]
    __shared__ double prod_s[128];   // n_t[kk] * q[kk]
    __shared__ double red_s[8][128]; // retr partials per k-row-group
    __shared__ double denom_s;

    const double ig = exp((double)pr[3072 + h]);
    const double fg = 1.0 / (1.0 + exp(-(double)pr[3080 + h]));

    if (t < 128) {
        const double qv = (double)pr[h * 128 + t];
        const double kv = (double)pr[1024 + h * 128 + t];
        q_s[t]    = qv;
        const double cf = ig * kv;
        coef_s[t] = cf;
        const double nv = fma(fg, (double)n_tm1[(size_t)b * 1024 + h * 128 + t], cf);
        out[NOFF + (size_t)b * 1024 + h * 128 + t] = (float)nv;
        prod_s[t] = nv * qv;
    }
    __syncthreads();

    const int g = t >> 5;   // k-row group 0..7
    const int s = t & 31;   // v float4 slot 0..31
    const float4* __restrict__ Cin  = (const float4*)(C_tm1 + (size_t)bh * 16384);
    float4*       __restrict__ Cout = (float4*)(out + COFF + (size_t)bh * 16384);
    const float4 vf = *(const float4*)(pr + 2048 + h * 128 + (s << 2));
    const double v0 = (double)vf.x, v1 = (double)vf.y, v2 = (double)vf.z, v3 = (double)vf.w;

    double r0 = 0.0, r1 = 0.0, r2 = 0.0, r3 = 0.0;
#pragma unroll 4
    for (int it = 0; it < 16; ++it) {
        const int kr = (it << 3) + g;
        const float4 cc = Cin[(kr << 5) + s];
        const double cf = coef_s[kr];
        const double qv = q_s[kr];
        const double c0 = fma(fg, (double)cc.x, cf * v0);
        const double c1 = fma(fg, (double)cc.y, cf * v1);
        const double c2 = fma(fg, (double)cc.z, cf * v2);
        const double c3 = fma(fg, (double)cc.w, cf * v3);
        float4 cn;
        cn.x = (float)c0; cn.y = (float)c1; cn.z = (float)c2; cn.w = (float)c3;
        Cout[(kr << 5) + s] = cn;
        r0 = fma(c0, qv, r0);
        r1 = fma(c1, qv, r1);
        r2 = fma(c2, qv, r2);
        r3 = fma(c3, qv, r3);
    }
    red_s[g][(s << 2) + 0] = r0;
    red_s[g][(s << 2) + 1] = r1;
    red_s[g][(s << 2) + 2] = r2;
    red_s[g][(s << 2) + 3] = r3;
    __syncthreads();

    // denom = sum_k n_t[k]*q[k] + 1e-8   (fp64: 128 -> 64 fold, wave reduce)
    if (t < 64) {
        double x = prod_s[t] + prod_s[t + 64];
#pragma unroll
        for (int off = 32; off > 0; off >>= 1) x += __shfl_xor(x, off, 64);
        if (t == 0) denom_s = x + 1e-8;
    }
    __syncthreads();

    // final retr reduction over 8 groups + h_t epilogue (threads 0..31)
    if (t < 32) {
        double r[4] = {0.0, 0.0, 0.0, 0.0};
#pragma unroll
        for (int gg = 0; gg < 8; ++gg) {
#pragma unroll
            for (int j = 0; j < 4; ++j) r[j] += red_s[gg][(t << 2) + j];
        }
        const double inv = 1.0 / denom_s;
        const float* oo = pr + 3088 + h * 128 + (t << 2);
        float4 hv;
        hv.x = (float)((1.0 / (1.0 + exp(-(double)oo[0]))) * (r[0] * inv));
        hv.y = (float)((1.0 / (1.0 + exp(-(double)oo[1]))) * (r[1] * inv));
        hv.z = (float)((1.0 / (1.0 + exp(-(double)oo[2]))) * (r[2] * inv));
        hv.w = (float)((1.0 / (1.0 + exp(-(double)oo[3]))) * (r[3] * inv));
        *(float4*)(out + HOFF + (size_t)b * 1024 + h * 128 + (t << 2)) = hv;
    }
}

// ---------------------------------------------------------------------------
extern "C" void kernel_launch(void* const* d_in, const int* in_sizes, int n_in,
                              void* d_out, int out_size, void* d_ws, size_t ws_size,
                              hipStream_t stream)
{
    const float* inputs  = (const float*)d_in[0];   // (512, 1024)
    const float* h_tm1   = (const float*)d_in[1];   // (512, 1024)
    const float* C_tm1   = (const float*)d_in[2];   // (512, 8*128*128)
    const float* n_tm1   = (const float*)d_in[3];   // (512, 8*128)
    const float* kernelW = (const float*)d_in[4];   // (1024, 4112)
    const float* rkernel = (const float*)d_in[5];   // (1024, 4112)
    const float* bias    = (const float*)d_in[6];   // (4112,)
    float* out  = (float*)d_out;
    float* proj = (float*)d_ws;                     // 512*4112 floats = 8.4 MB

    proj_gemm<<<dim3(64, 8), dim3(256), 0, stream>>>(inputs, h_tm1, kernelW, rkernel, bias, proj);
    proj_tail<<<dim3(32), dim3(256), 0, stream>>>(inputs, h_tm1, kernelW, rkernel, bias, proj);
    mlstm_update<<<dim3(4096), dim3(256), 0, stream>>>(proj, C_tm1, n_tm1, out);
}

// Round 6
// 352.324 us; speedup vs baseline: 1.9357x; 1.9357x over previous
//
#include <hip/hip_runtime.h>
#include <math.h>

// Problem constants
#define NPROJ 4112          // P = 2*H*K + H*V + 2*H + UNITS
#define HOFF  0                                  // h_t  : 512*1024
#define COFF  524288                             // C_t  : 512*8*128*128
#define NOFF  67633152                           // n_t  : 512*1024

// ---------------------------------------------------------------------------
// Kernel 1: split-K fp32 GEMM.  partial[z] = Xsrc @ Wsrc over a 512-k slice.
//   z=0: X0,W0 k[0,512)   z=1: X0,W0 k[512,1024)
//   z=2: X1,W1 k[0,512)   z=3: X1,W1 k[512,1024)
// BM=64, BN=64, BK=16, 256 threads, 4x4/thread. fp32 FMA, 32-term chunks
// flushed to fp64 (R3-proven numerics: absmax 64). Grid (64,8,4)=2048 blocks
// = 8 blocks/CU -> 32 waves/CU (R3 had only 2 blocks/CU, VALUBusy 33%).
// Cols 0..4095 only; tail cols handled by proj_tail.
// ---------------------------------------------------------------------------
__global__ __launch_bounds__(256)
void proj_gemm_sk(const float* __restrict__ X0, const float* __restrict__ X1,
                  const float* __restrict__ W0, const float* __restrict__ W1,
                  float* __restrict__ pbuf)
{
    const int K = 1024;
    __shared__ float As[16][68];
    __shared__ float Bs[16][68];

    const int tid  = threadIdx.x;
    const int row0 = blockIdx.y * 64;
    const int col0 = blockIdx.x * 64;          // 0..4032 (cols < 4096 always)
    const int z    = blockIdx.z;
    const float* __restrict__ A = (z < 2) ? X0 : X1;
    const float* __restrict__ W = (z < 2) ? W0 : W1;
    const int kbase = (z & 1) << 9;            // 0 or 512
    const int tx = tid & 15, ty = tid >> 4;

    float  acc32[4][4];
    double acc64[4][4];
#pragma unroll
    for (int i = 0; i < 4; ++i)
#pragma unroll
        for (int j = 0; j < 4; ++j) { acc32[i][j] = 0.f; acc64[i][j] = 0.0; }

    for (int kt = 0; kt < 32; ++kt) {
        const int k0 = kbase + (kt << 4);
        // stage A tile: 64 rows x 16 k (256 threads, one float4 each)
        {
            const int r  = tid >> 2;
            const int kq = (tid & 3) << 2;
            const float4 a = *(const float4*)(A + (size_t)(row0 + r) * K + k0 + kq);
            As[kq + 0][r] = a.x; As[kq + 1][r] = a.y;
            As[kq + 2][r] = a.z; As[kq + 3][r] = a.w;
        }
        // stage B tile: 16 k x 64 n (256 threads, one float4 each; no guard)
        {
            const int kr = tid >> 4;
            const int nc = (tid & 15) << 2;
            *(float4*)&Bs[kr][nc] = *(const float4*)(W + (size_t)(k0 + kr) * NPROJ + col0 + nc);
        }
        __syncthreads();
#pragma unroll
        for (int kk = 0; kk < 16; ++kk) {
            const float4 av = *(const float4*)&As[kk][ty << 2];
            const float4 bv = *(const float4*)&Bs[kk][tx << 2];
            const float aa[4] = {av.x, av.y, av.z, av.w};
            const float bb[4] = {bv.x, bv.y, bv.z, bv.w};
#pragma unroll
            for (int i = 0; i < 4; ++i)
#pragma unroll
                for (int j = 0; j < 4; ++j)
                    acc32[i][j] = fmaf(aa[i], bb[j], acc32[i][j]);
        }
        __syncthreads();
        if (kt & 1) {   // flush 32-k fp32 chunk into fp64 (R3-proven cadence)
#pragma unroll
            for (int i = 0; i < 4; ++i)
#pragma unroll
                for (int j = 0; j < 4; ++j) {
                    acc64[i][j] += (double)acc32[i][j];
                    acc32[i][j] = 0.f;
                }
        }
    }

    // store fp32 partial to pbuf[z] (dense [512][4096] per slice)
    float* __restrict__ dst = pbuf + ((size_t)z << 21);   // z * 512*4096
    const int c = col0 + (tx << 2);
#pragma unroll
    for (int i = 0; i < 4; ++i) {
        const int row = row0 + (ty << 2) + i;
        float4 w;
        w.x = (float)acc64[i][0];
        w.y = (float)acc64[i][1];
        w.z = (float)acc64[i][2];
        w.w = (float)acc64[i][3];
        *(float4*)(dst + (size_t)row * 4096 + c) = w;
    }
}

// ---------------------------------------------------------------------------
// Kernel 1r: reduce 4 partials (fp64) + bias -> proj[:, 0:4096]
// 2048 blocks x 256 threads, one float4 per thread.
// ---------------------------------------------------------------------------
__global__ __launch_bounds__(256)
void proj_reduce(const float* __restrict__ pbuf, const float* __restrict__ bias,
                 float* __restrict__ proj)
{
    const int i4   = blockIdx.x * 256 + threadIdx.x;   // 0..524287
    const int flat = i4 << 2;
    const int row  = flat >> 12;
    const int col  = flat & 4095;
    const float4 p0 = *(const float4*)(pbuf + flat);
    const float4 p1 = *(const float4*)(pbuf + (1u << 21) + flat);
    const float4 p2 = *(const float4*)(pbuf + (2u << 21) + flat);
    const float4 p3 = *(const float4*)(pbuf + (3u << 21) + flat);
    const float4 bv = *(const float4*)(bias + col);
    float4 w;
    w.x = (float)((((double)p0.x + (double)p1.x) + ((double)p2.x + (double)p3.x)) + (double)bv.x);
    w.y = (float)((((double)p0.y + (double)p1.y) + ((double)p2.y + (double)p3.y)) + (double)bv.y);
    w.z = (float)((((double)p0.z + (double)p1.z) + ((double)p2.z + (double)p3.z)) + (double)bv.z);
    w.w = (float)((((double)p0.w + (double)p1.w) + ((double)p2.w + (double)p3.w)) + (double)bv.w);
    *(float4*)(proj + (size_t)row * NPROJ + col) = w;
}

// ---------------------------------------------------------------------------
// Kernel 1b: tail columns 4096..4111 (o_g tail — cancellation-insensitive).
// ---------------------------------------------------------------------------
__global__ __launch_bounds__(256)
void proj_tail(const float* __restrict__ X0, const float* __restrict__ X1,
               const float* __restrict__ W0, const float* __restrict__ W1,
               const float* __restrict__ bias, float* __restrict__ proj)
{
    const int tid = threadIdx.x;
    const int r   = (blockIdx.x << 4) + (tid >> 4);   // 0..511
    const int c   = 4096 + (tid & 15);
    double acc = 0.0;
    for (int src = 0; src < 2; ++src) {
        const float* __restrict__ X = src ? X1 : X0;
        const float* __restrict__ W = src ? W1 : W0;
        const float* __restrict__ xr = X + (size_t)r * 1024;
        for (int kc = 0; kc < 4; ++kc) {
            float s0 = 0.f, s1 = 0.f, s2 = 0.f, s3 = 0.f;
            const int kend = (kc << 8) + 256;
#pragma unroll 8
            for (int k = kc << 8; k < kend; k += 4) {
                const float4 xv = *(const float4*)(xr + k);
                s0 = fmaf(xv.x, W[(size_t)(k + 0) * NPROJ + c], s0);
                s1 = fmaf(xv.y, W[(size_t)(k + 1) * NPROJ + c], s1);
                s2 = fmaf(xv.z, W[(size_t)(k + 2) * NPROJ + c], s2);
                s3 = fmaf(xv.w, W[(size_t)(k + 3) * NPROJ + c], s3);
            }
            acc += (double)((s0 + s1) + (s2 + s3));
        }
    }
    proj[(size_t)r * NPROJ + c] = (float)(acc + (double)bias[c]);
}

// ---------------------------------------------------------------------------
// Fallback fp32 GEMM (proven R3: 240us, absmax 64) — used if ws too small.
// ---------------------------------------------------------------------------
__global__ __launch_bounds__(256)
void proj_gemm_fp32(const float* __restrict__ X0, const float* __restrict__ X1,
                    const float* __restrict__ W0, const float* __restrict__ W1,
                    const float* __restrict__ bias, float* __restrict__ proj)
{
    const int N = NPROJ;
    const int K = 1024;
    __shared__ float As[16][68];
    __shared__ float Bs[16][68];
    const int tid  = threadIdx.x;
    const int row0 = blockIdx.y * 64;
    const int col0 = blockIdx.x * 64;
    const int tx   = tid & 15;
    const int ty   = tid >> 4;
    float  acc32[4][4];
    double acc64[4][4];
#pragma unroll
    for (int i = 0; i < 4; ++i)
#pragma unroll
        for (int j = 0; j < 4; ++j) { acc32[i][j] = 0.f; acc64[i][j] = 0.0; }
    for (int src = 0; src < 2; ++src) {
        const float* __restrict__ A = src ? X1 : X0;
        const float* __restrict__ W = src ? W1 : W0;
        for (int kt = 0; kt < 64; ++kt) {
            const int k0 = kt << 4;
            {
                const int r  = tid >> 2;
                const int kq = (tid & 3) << 2;
                const float4 a = *(const float4*)(A + (size_t)(row0 + r) * K + k0 + kq);
                As[kq + 0][r] = a.x; As[kq + 1][r] = a.y;
                As[kq + 2][r] = a.z; As[kq + 3][r] = a.w;
            }
            {
                const int kr = tid >> 4;
                const int nc = (tid & 15) << 2;
                const int gn = col0 + nc;
                float4 bv = make_float4(0.f, 0.f, 0.f, 0.f);
                if (gn < N) bv = *(const float4*)(W + (size_t)(k0 + kr) * N + gn);
                *(float4*)&Bs[kr][nc] = bv;
            }
            __syncthreads();
#pragma unroll
            for (int kk = 0; kk < 16; ++kk) {
                const float4 av = *(const float4*)&As[kk][ty << 2];
                const float4 bv = *(const float4*)&Bs[kk][tx << 2];
                const float aa[4] = {av.x, av.y, av.z, av.w};
                const float bb[4] = {bv.x, bv.y, bv.z, bv.w};
#pragma unroll
                for (int i = 0; i < 4; ++i)
#pragma unroll
                    for (int j = 0; j < 4; ++j)
                        acc32[i][j] = fmaf(aa[i], bb[j], acc32[i][j]);
            }
            __syncthreads();
            if (kt & 1) {
#pragma unroll
                for (int i = 0; i < 4; ++i)
#pragma unroll
                    for (int j = 0; j < 4; ++j) {
                        acc64[i][j] += (double)acc32[i][j];
                        acc32[i][j] = 0.f;
                    }
            }
        }
    }
    const int c = col0 + (tx << 2);
    if (c < N) {
#pragma unroll
        for (int i = 0; i < 4; ++i) {
            const int row = row0 + (ty << 2) + i;
            float4 w;
            w.x = (float)(acc64[i][0] + (double)bias[c + 0]);
            w.y = (float)(acc64[i][1] + (double)bias[c + 1]);
            w.z = (float)(acc64[i][2] + (double)bias[c + 2]);
            w.w = (float)(acc64[i][3] + (double)bias[c + 3]);
            *(float4*)(proj + (size_t)row * N + c) = w;
        }
    }
}

// ---------------------------------------------------------------------------
// Kernel 2: fused mLSTM state update (HBM-bound, ~78us, fp64 internals).
// ---------------------------------------------------------------------------
__global__ __launch_bounds__(256)
void mlstm_update(const float* __restrict__ proj, const float* __restrict__ C_tm1,
                  const float* __restrict__ n_tm1, float* __restrict__ out)
{
    const int bh = blockIdx.x;
    const int b  = bh >> 3;
    const int h  = bh & 7;
    const int t  = threadIdx.x;
    const float* __restrict__ pr = proj + (size_t)b * NPROJ;

    __shared__ double q_s[128];
    __shared__ double coef_s[128];
    __shared__ double prod_s[128];
    __shared__ double red_s[8][128];
    __shared__ double denom_s;

    const double ig = exp((double)pr[3072 + h]);
    const double fg = 1.0 / (1.0 + exp(-(double)pr[3080 + h]));

    if (t < 128) {
        const double qv = (double)pr[h * 128 + t];
        const double kv = (double)pr[1024 + h * 128 + t];
        q_s[t]    = qv;
        const double cf = ig * kv;
        coef_s[t] = cf;
        const double nv = fma(fg, (double)n_tm1[(size_t)b * 1024 + h * 128 + t], cf);
        out[NOFF + (size_t)b * 1024 + h * 128 + t] = (float)nv;
        prod_s[t] = nv * qv;
    }
    __syncthreads();

    const int g = t >> 5;
    const int s = t & 31;
    const float4* __restrict__ Cin  = (const float4*)(C_tm1 + (size_t)bh * 16384);
    float4*       __restrict__ Cout = (float4*)(out + COFF + (size_t)bh * 16384);
    const float4 vf = *(const float4*)(pr + 2048 + h * 128 + (s << 2));
    const double v0 = (double)vf.x, v1 = (double)vf.y, v2 = (double)vf.z, v3 = (double)vf.w;

    double r0 = 0.0, r1 = 0.0, r2 = 0.0, r3 = 0.0;
#pragma unroll 4
    for (int it = 0; it < 16; ++it) {
        const int kr = (it << 3) + g;
        const float4 cc = Cin[(kr << 5) + s];
        const double cf = coef_s[kr];
        const double qv = q_s[kr];
        const double c0 = fma(fg, (double)cc.x, cf * v0);
        const double c1 = fma(fg, (double)cc.y, cf * v1);
        const double c2 = fma(fg, (double)cc.z, cf * v2);
        const double c3 = fma(fg, (double)cc.w, cf * v3);
        float4 cn;
        cn.x = (float)c0; cn.y = (float)c1; cn.z = (float)c2; cn.w = (float)c3;
        Cout[(kr << 5) + s] = cn;
        r0 = fma(c0, qv, r0);
        r1 = fma(c1, qv, r1);
        r2 = fma(c2, qv, r2);
        r3 = fma(c3, qv, r3);
    }
    red_s[g][(s << 2) + 0] = r0;
    red_s[g][(s << 2) + 1] = r1;
    red_s[g][(s << 2) + 2] = r2;
    red_s[g][(s << 2) + 3] = r3;
    __syncthreads();

    if (t < 64) {
        double x = prod_s[t] + prod_s[t + 64];
#pragma unroll
        for (int off = 32; off > 0; off >>= 1) x += __shfl_xor(x, off, 64);
        if (t == 0) denom_s = x + 1e-8;
    }
    __syncthreads();

    if (t < 32) {
        double r[4] = {0.0, 0.0, 0.0, 0.0};
#pragma unroll
        for (int gg = 0; gg < 8; ++gg) {
#pragma unroll
            for (int j = 0; j < 4; ++j) r[j] += red_s[gg][(t << 2) + j];
        }
        const double inv = 1.0 / denom_s;
        const float* oo = pr + 3088 + h * 128 + (t << 2);
        float4 hv;
        hv.x = (float)((1.0 / (1.0 + exp(-(double)oo[0]))) * (r[0] * inv));
        hv.y = (float)((1.0 / (1.0 + exp(-(double)oo[1]))) * (r[1] * inv));
        hv.z = (float)((1.0 / (1.0 + exp(-(double)oo[2]))) * (r[2] * inv));
        hv.w = (float)((1.0 / (1.0 + exp(-(double)oo[3]))) * (r[3] * inv));
        *(float4*)(out + HOFF + (size_t)b * 1024 + h * 128 + (t << 2)) = hv;
    }
}

// ---------------------------------------------------------------------------
extern "C" void kernel_launch(void* const* d_in, const int* in_sizes, int n_in,
                              void* d_out, int out_size, void* d_ws, size_t ws_size,
                              hipStream_t stream)
{
    const float* inputs  = (const float*)d_in[0];   // (512, 1024)
    const float* h_tm1   = (const float*)d_in[1];   // (512, 1024)
    const float* C_tm1   = (const float*)d_in[2];   // (512, 8*128*128)
    const float* n_tm1   = (const float*)d_in[3];   // (512, 8*128)
    const float* kernelW = (const float*)d_in[4];   // (1024, 4112)
    const float* rkernel = (const float*)d_in[5];   // (1024, 4112)
    const float* bias    = (const float*)d_in[6];   // (4112,)
    float* out  = (float*)d_out;
    float* proj = (float*)d_ws;                     // 512*4112 f32 = 8.42 MB

    const size_t SZ_PROJ = (size_t)512 * NPROJ * 4;            // 8,421,376
    const size_t SZ_PART = (size_t)4 * 512 * 4096 * 4;         // 33,554,432
    const size_t NEED    = SZ_PROJ + SZ_PART;                  // ~42 MB

    if (ws_size >= NEED) {
        float* pbuf = (float*)((char*)d_ws + SZ_PROJ);
        proj_gemm_sk<<<dim3(64, 8, 4), dim3(256), 0, stream>>>(inputs, h_tm1, kernelW, rkernel, pbuf);
        proj_reduce<<<dim3(2048), dim3(256), 0, stream>>>(pbuf, bias, proj);
        proj_tail<<<dim3(32), dim3(256), 0, stream>>>(inputs, h_tm1, kernelW, rkernel, bias, proj);
    } else {
        proj_gemm_fp32<<<dim3(65, 8), dim3(256), 0, stream>>>(inputs, h_tm1, kernelW, rkernel, bias, proj);
    }
    mlstm_update<<<dim3(4096), dim3(256), 0, stream>>>(proj, C_tm1, n_tm1, out);
}

// Round 7
// 248.384 us; speedup vs baseline: 2.7458x; 1.4185x over previous
//
#include <hip/hip_runtime.h>
#include <math.h>

// Problem constants
#define NPROJ 4112          // P = 2*H*K + H*V + 2*H + UNITS
#define HOFF  0                                  // h_t  : 512*1024
#define COFF  524288                             // C_t  : 512*8*128*128
#define NOFF  67633152                           // n_t  : 512*1024
#define SLICE 2105344                            // 512*4112 (one split-K partial)

// ---------------------------------------------------------------------------
// Kernel 1: split-K fp32 GEMM over ALL 4112 cols (guarded 65th col tile).
//   z=0: X0,W0 k[0,512)   z=1: X0,W0 k[512,1024)
//   z=2: X1,W1 k[0,512)   z=3: X1,W1 k[512,1024)
// BM=64, BN=64, BK=32, 256 threads, 4x4/thread. fp32 FMA, 32-term chunks
// flushed to fp64 (proven cadence: absmax 32-64). Grid (65,8,4)=2080 blocks
// ~ 8 blocks/CU -> 32 waves/CU. One flush per K-tile, 2 barriers per K-tile.
// ---------------------------------------------------------------------------
__global__ __launch_bounds__(256)
void proj_gemm_sk(const float* __restrict__ X0, const float* __restrict__ X1,
                  const float* __restrict__ W0, const float* __restrict__ W1,
                  float* __restrict__ pbuf)
{
    const int K = 1024;
    const int N = NPROJ;
    __shared__ float As[32][68];   // [k][row]
    __shared__ float Bs[32][68];   // [k][col]

    const int tid  = threadIdx.x;
    const int row0 = blockIdx.y * 64;
    const int col0 = blockIdx.x * 64;          // 0..4096 (last tile has 16 cols)
    const int z    = blockIdx.z;
    const float* __restrict__ A = (z < 2) ? X0 : X1;
    const float* __restrict__ W = (z < 2) ? W0 : W1;
    const int kbase = (z & 1) << 9;            // 0 or 512
    const int tx = tid & 15, ty = tid >> 4;

    // staging assignment
    const int ar = tid >> 2;                   // A row 0..63
    const int aq = (tid & 3) << 2;             // A k-quad {0,4,8,12} (+16)
    const int bk = tid >> 4;                   // B k-row 0..15 (+16)
    const int bn = (tid & 15) << 2;            // B col 0..60
    const int gn = col0 + bn;
    const bool bok = gn < N;

    float  acc32[4][4];
    double acc64[4][4];
#pragma unroll
    for (int i = 0; i < 4; ++i)
#pragma unroll
        for (int j = 0; j < 4; ++j) { acc32[i][j] = 0.f; acc64[i][j] = 0.0; }

    for (int kt = 0; kt < 16; ++kt) {
        const int k0 = kbase + (kt << 5);
        // stage A: 64 rows x 32 k (2 float4 per thread, scalar transpose-writes)
        {
            const float4 a0 = *(const float4*)(A + (size_t)(row0 + ar) * K + k0 + aq);
            const float4 a1 = *(const float4*)(A + (size_t)(row0 + ar) * K + k0 + aq + 16);
            As[aq + 0][ar] = a0.x; As[aq + 1][ar] = a0.y;
            As[aq + 2][ar] = a0.z; As[aq + 3][ar] = a0.w;
            As[aq + 16][ar] = a1.x; As[aq + 17][ar] = a1.y;
            As[aq + 18][ar] = a1.z; As[aq + 19][ar] = a1.w;
        }
        // stage B: 32 k x 64 n (2 float4 per thread, guarded zero-fill)
        {
            float4 b0 = make_float4(0.f, 0.f, 0.f, 0.f), b1 = b0;
            if (bok) {
                b0 = *(const float4*)(W + (size_t)(k0 + bk) * N + gn);
                b1 = *(const float4*)(W + (size_t)(k0 + bk + 16) * N + gn);
            }
            *(float4*)&Bs[bk][bn]      = b0;
            *(float4*)&Bs[bk + 16][bn] = b1;
        }
        __syncthreads();
#pragma unroll
        for (int kk = 0; kk < 32; ++kk) {
            const float4 av = *(const float4*)&As[kk][ty << 2];
            const float4 bv = *(const float4*)&Bs[kk][tx << 2];
            const float aa[4] = {av.x, av.y, av.z, av.w};
            const float bb[4] = {bv.x, bv.y, bv.z, bv.w};
#pragma unroll
            for (int i = 0; i < 4; ++i)
#pragma unroll
                for (int j = 0; j < 4; ++j)
                    acc32[i][j] = fmaf(aa[i], bb[j], acc32[i][j]);
        }
        __syncthreads();
        // flush 32-k fp32 chunk into fp64 (proven cadence)
#pragma unroll
        for (int i = 0; i < 4; ++i)
#pragma unroll
            for (int j = 0; j < 4; ++j) {
                acc64[i][j] += (double)acc32[i][j];
                acc32[i][j] = 0.f;
            }
    }

    // store fp32 partial to pbuf[z] (dense [512][4112] per slice, guarded)
    float* __restrict__ dst = pbuf + (size_t)z * SLICE;
    const int c = col0 + (tx << 2);
    if (c < N) {
#pragma unroll
        for (int i = 0; i < 4; ++i) {
            const int row = row0 + (ty << 2) + i;
            float4 w;
            w.x = (float)acc64[i][0];
            w.y = (float)acc64[i][1];
            w.z = (float)acc64[i][2];
            w.w = (float)acc64[i][3];
            *(float4*)(dst + (size_t)row * N + c) = w;
        }
    }
}

// ---------------------------------------------------------------------------
// Kernel 1r: reduce 4 partials (fp64) + bias -> proj (all 4112 cols).
// proj and pbuf slices share the dense [512][4112] layout; linear indexing.
// 2056 blocks x 256 threads, one float4 per thread.
// ---------------------------------------------------------------------------
__global__ __launch_bounds__(256)
void proj_reduce(const float* __restrict__ pbuf, const float* __restrict__ bias,
                 float* __restrict__ proj)
{
    const int i4 = blockIdx.x * 256 + threadIdx.x;   // 0..526335
    const int f  = i4 << 2;                          // flat float index
    const int col = f % NPROJ;                       // rows are 16B-aligned (4112%4==0)
    const float4 p0 = *(const float4*)(pbuf + f);
    const float4 p1 = *(const float4*)(pbuf + SLICE + f);
    const float4 p2 = *(const float4*)(pbuf + 2 * (size_t)SLICE + f);
    const float4 p3 = *(const float4*)(pbuf + 3 * (size_t)SLICE + f);
    const float4 bv = *(const float4*)(bias + col);
    float4 w;
    w.x = (float)((((double)p0.x + (double)p1.x) + ((double)p2.x + (double)p3.x)) + (double)bv.x);
    w.y = (float)((((double)p0.y + (double)p1.y) + ((double)p2.y + (double)p3.y)) + (double)bv.y);
    w.z = (float)((((double)p0.z + (double)p1.z) + ((double)p2.z + (double)p3.z)) + (double)bv.z);
    w.w = (float)((((double)p0.w + (double)p1.w) + ((double)p2.w + (double)p3.w)) + (double)bv.w);
    *(float4*)(proj + f) = w;
}

// ---------------------------------------------------------------------------
// Fallback fp32 GEMM (proven R3: 240us, absmax 64) — used if ws too small.
// ---------------------------------------------------------------------------
__global__ __launch_bounds__(256)
void proj_gemm_fp32(const float* __restrict__ X0, const float* __restrict__ X1,
                    const float* __restrict__ W0, const float* __restrict__ W1,
                    const float* __restrict__ bias, float* __restrict__ proj)
{
    const int N = NPROJ;
    const int K = 1024;
    __shared__ float As[16][68];
    __shared__ float Bs[16][68];
    const int tid  = threadIdx.x;
    const int row0 = blockIdx.y * 64;
    const int col0 = blockIdx.x * 64;
    const int tx   = tid & 15;
    const int ty   = tid >> 4;
    float  acc32[4][4];
    double acc64[4][4];
#pragma unroll
    for (int i = 0; i < 4; ++i)
#pragma unroll
        for (int j = 0; j < 4; ++j) { acc32[i][j] = 0.f; acc64[i][j] = 0.0; }
    for (int src = 0; src < 2; ++src) {
        const float* __restrict__ A = src ? X1 : X0;
        const float* __restrict__ W = src ? W1 : W0;
        for (int kt = 0; kt < 64; ++kt) {
            const int k0 = kt << 4;
            {
                const int r  = tid >> 2;
                const int kq = (tid & 3) << 2;
                const float4 a = *(const float4*)(A + (size_t)(row0 + r) * K + k0 + kq);
                As[kq + 0][r] = a.x; As[kq + 1][r] = a.y;
                As[kq + 2][r] = a.z; As[kq + 3][r] = a.w;
            }
            {
                const int kr = tid >> 4;
                const int nc = (tid & 15) << 2;
                const int gn = col0 + nc;
                float4 bv = make_float4(0.f, 0.f, 0.f, 0.f);
                if (gn < N) bv = *(const float4*)(W + (size_t)(k0 + kr) * N + gn);
                *(float4*)&Bs[kr][nc] = bv;
            }
            __syncthreads();
#pragma unroll
            for (int kk = 0; kk < 16; ++kk) {
                const float4 av = *(const float4*)&As[kk][ty << 2];
                const float4 bv = *(const float4*)&Bs[kk][tx << 2];
                const float aa[4] = {av.x, av.y, av.z, av.w};
                const float bb[4] = {bv.x, bv.y, bv.z, bv.w};
#pragma unroll
                for (int i = 0; i < 4; ++i)
#pragma unroll
                    for (int j = 0; j < 4; ++j)
                        acc32[i][j] = fmaf(aa[i], bb[j], acc32[i][j]);
            }
            __syncthreads();
            if (kt & 1) {
#pragma unroll
                for (int i = 0; i < 4; ++i)
#pragma unroll
                    for (int j = 0; j < 4; ++j) {
                        acc64[i][j] += (double)acc32[i][j];
                        acc32[i][j] = 0.f;
                    }
            }
        }
    }
    const int c = col0 + (tx << 2);
    if (c < N) {
#pragma unroll
        for (int i = 0; i < 4; ++i) {
            const int row = row0 + (ty << 2) + i;
            float4 w;
            w.x = (float)(acc64[i][0] + (double)bias[c + 0]);
            w.y = (float)(acc64[i][1] + (double)bias[c + 1]);
            w.z = (float)(acc64[i][2] + (double)bias[c + 2]);
            w.w = (float)(acc64[i][3] + (double)bias[c + 3]);
            *(float4*)(proj + (size_t)row * N + c) = w;
        }
    }
}

// ---------------------------------------------------------------------------
// Kernel 2: fused mLSTM state update (HBM-bound, ~78us, fp64 internals).
// ---------------------------------------------------------------------------
__global__ __launch_bounds__(256)
void mlstm_update(const float* __restrict__ proj, const float* __restrict__ C_tm1,
                  const float* __restrict__ n_tm1, float* __restrict__ out)
{
    const int bh = blockIdx.x;
    const int b  = bh >> 3;
    const int h  = bh & 7;
    const int t  = threadIdx.x;
    const float* __restrict__ pr = proj + (size_t)b * NPROJ;

    __shared__ double q_s[128];
    __shared__ double coef_s[128];
    __shared__ double prod_s[128];
    __shared__ double red_s[8][128];
    __shared__ double denom_s;

    const double ig = exp((double)pr[3072 + h]);
    const double fg = 1.0 / (1.0 + exp(-(double)pr[3080 + h]));

    if (t < 128) {
        const double qv = (double)pr[h * 128 + t];
        const double kv = (double)pr[1024 + h * 128 + t];
        q_s[t]    = qv;
        const double cf = ig * kv;
        coef_s[t] = cf;
        const double nv = fma(fg, (double)n_tm1[(size_t)b * 1024 + h * 128 + t], cf);
        out[NOFF + (size_t)b * 1024 + h * 128 + t] = (float)nv;
        prod_s[t] = nv * qv;
    }
    __syncthreads();

    const int g = t >> 5;
    const int s = t & 31;
    const float4* __restrict__ Cin  = (const float4*)(C_tm1 + (size_t)bh * 16384);
    float4*       __restrict__ Cout = (float4*)(out + COFF + (size_t)bh * 16384);
    const float4 vf = *(const float4*)(pr + 2048 + h * 128 + (s << 2));
    const double v0 = (double)vf.x, v1 = (double)vf.y, v2 = (double)vf.z, v3 = (double)vf.w;

    double r0 = 0.0, r1 = 0.0, r2 = 0.0, r3 = 0.0;
#pragma unroll 4
    for (int it = 0; it < 16; ++it) {
        const int kr = (it << 3) + g;
        const float4 cc = Cin[(kr << 5) + s];
        const double cf = coef_s[kr];
        const double qv = q_s[kr];
        const double c0 = fma(fg, (double)cc.x, cf * v0);
        const double c1 = fma(fg, (double)cc.y, cf * v1);
        const double c2 = fma(fg, (double)cc.z, cf * v2);
        const double c3 = fma(fg, (double)cc.w, cf * v3);
        float4 cn;
        cn.x = (float)c0; cn.y = (float)c1; cn.z = (float)c2; cn.w = (float)c3;
        Cout[(kr << 5) + s] = cn;
        r0 = fma(c0, qv, r0);
        r1 = fma(c1, qv, r1);
        r2 = fma(c2, qv, r2);
        r3 = fma(c3, qv, r3);
    }
    red_s[g][(s << 2) + 0] = r0;
    red_s[g][(s << 2) + 1] = r1;
    red_s[g][(s << 2) + 2] = r2;
    red_s[g][(s << 2) + 3] = r3;
    __syncthreads();

    if (t < 64) {
        double x = prod_s[t] + prod_s[t + 64];
#pragma unroll
        for (int off = 32; off > 0; off >>= 1) x += __shfl_xor(x, off, 64);
        if (t == 0) denom_s = x + 1e-8;
    }
    __syncthreads();

    if (t < 32) {
        double r[4] = {0.0, 0.0, 0.0, 0.0};
#pragma unroll
        for (int gg = 0; gg < 8; ++gg) {
#pragma unroll
            for (int j = 0; j < 4; ++j) r[j] += red_s[gg][(t << 2) + j];
        }
        const double inv = 1.0 / denom_s;
        const float* oo = pr + 3088 + h * 128 + (t << 2);
        float4 hv;
        hv.x = (float)((1.0 / (1.0 + exp(-(double)oo[0]))) * (r[0] * inv));
        hv.y = (float)((1.0 / (1.0 + exp(-(double)oo[1]))) * (r[1] * inv));
        hv.z = (float)((1.0 / (1.0 + exp(-(double)oo[2]))) * (r[2] * inv));
        hv.w = (float)((1.0 / (1.0 + exp(-(double)oo[3]))) * (r[3] * inv));
        *(float4*)(out + HOFF + (size_t)b * 1024 + h * 128 + (t << 2)) = hv;
    }
}

// ---------------------------------------------------------------------------
extern "C" void kernel_launch(void* const* d_in, const int* in_sizes, int n_in,
                              void* d_out, int out_size, void* d_ws, size_t ws_size,
                              hipStream_t stream)
{
    const float* inputs  = (const float*)d_in[0];   // (512, 1024)
    const float* h_tm1   = (const float*)d_in[1];   // (512, 1024)
    const float* C_tm1   = (const float*)d_in[2];   // (512, 8*128*128)
    const float* n_tm1   = (const float*)d_in[3];   // (512, 8*128)
    const float* kernelW = (const float*)d_in[4];   // (1024, 4112)
    const float* rkernel = (const float*)d_in[5];   // (1024, 4112)
    const float* bias    = (const float*)d_in[6];   // (4112,)
    float* out  = (float*)d_out;
    float* proj = (float*)d_ws;                     // 512*4112 f32 = 8.42 MB

    const size_t SZ_PROJ = (size_t)SLICE * 4;                  // 8,421,376
    const size_t SZ_PART = (size_t)4 * SLICE * 4;              // 33,685,504
    const size_t NEED    = SZ_PROJ + SZ_PART;                  // ~42.1 MB

    if (ws_size >= NEED) {
        float* pbuf = (float*)((char*)d_ws + SZ_PROJ);
        proj_gemm_sk<<<dim3(65, 8, 4), dim3(256), 0, stream>>>(inputs, h_tm1, kernelW, rkernel, pbuf);
        proj_reduce<<<dim3(2056), dim3(256), 0, stream>>>(pbuf, bias, proj);
    } else {
        proj_gemm_fp32<<<dim3(65, 8), dim3(256), 0, stream>>>(inputs, h_tm1, kernelW, rkernel, bias, proj);
    }
    mlstm_update<<<dim3(4096), dim3(256), 0, stream>>>(proj, C_tm1, n_tm1, out);
}